// Round 4
// baseline (71.932 us; speedup 1.0000x reference)
//
#include <hip/hip_runtime.h>

typedef __attribute__((ext_vector_type(8))) short   bf16x8;
typedef __attribute__((ext_vector_type(4))) float   f32x4;
typedef __attribute__((ext_vector_type(4))) unsigned int u32x4;

#define HT    8       // output rows per block
#define WSPAN 66      // staged w columns: 64 + 2 halo
#define NROWS (HT + 2)

__device__ __forceinline__ unsigned short f2bf(float f) {
    union { float f; unsigned u; } v; v.f = f;
    unsigned u = v.u;
    u += 0x7FFFu + ((u >> 16) & 1u);   // RNE
    return (unsigned short)(u >> 16);
}

// Barrier WITHOUT the compiler's vmcnt(0) drain: only LDS ops must be
// visible across it; in-flight global loads (wave-private VGPR dests) ride
// through. "memory" clobbers pin ds_read/ds_write on their side.
__device__ __forceinline__ void rowsync() {
    asm volatile("s_waitcnt lgkmcnt(0)" ::: "memory");
    __builtin_amdgcn_s_barrier();
    asm volatile("" ::: "memory");
}

__global__ __launch_bounds__(256, 2)
void conv3x3_mfma(const float* __restrict__ x, const float* __restrict__ wk,
                  float* __restrict__ out) {
    const int hb = blockIdx.x, wh = blockIdx.y, n = blockIdx.z;
    const int H0 = hb * HT, W0 = wh * 64;
    const int tid  = threadIdx.x;
    const int lane = tid & 63, wid = tid >> 6;
    const int lq = lane >> 4, lr = lane & 15;

    // 4 row-slots x 66 w x 32 c (bf16); each (slot,w) row = 64B = 4 x u32x4
    __shared__ u32x4 lds[4 * WSPAN * 4];

    // ---- weights -> registers: wave `wid` owns och tile [wid*16, wid*16+16) ----
    // Raw buffer index: ((c*3+ki)*3+kj)*64 + o   (reshape quirk).
    bf16x8 wA[9];
    #pragma unroll
    for (int p = 0; p < 9; ++p) {
        const int ki = p / 3, kj = p % 3;
        union { bf16x8 v; unsigned short s[8]; } u;
        #pragma unroll
        for (int j = 0; j < 8; ++j) {
            const int c = lq * 8 + j;
            u.s[j] = f2bf(wk[((c * 3 + ki) * 3 + kj) * 64 + wid * 16 + lr]);
        }
        wA[p] = u.v;
    }

    // ---- staging tasks ----
    // task A: every thread: (cb = tid>>6, wq = tid&63)
    // task B: threads 0..7: (cb = tid>>1, wq = 64+(tid&1))
    const int cb0 = tid >> 6, wq0 = tid & 63;
    const bool hasB = (tid < 8);
    const int cb1 = tid >> 1, wq1 = 64 + (tid & 1);

    auto issue_loads = [&](int rg, int cb, int wq, float (&dst)[8]) {
        const int wg = W0 - 1 + wq;
        const bool ok = ((unsigned)rg < 128u) && ((unsigned)wg < 128u);
        const float* p = x + (((n * 32 + cb * 8) * 128 + rg) * 128 + wg);
        #pragma unroll
        for (int j = 0; j < 8; ++j)
            dst[j] = ok ? p[j * 16384] : 0.0f;   // channel stride = H*W
    };
    // swizzle f=(wq>>1)&3: every 8 consecutive lanes hit 8 distinct bank-quads
    // for BOTH writes (wq consecutive in tid) and reads (wq consecutive in lr).
    auto lds_write = [&](int slot, int cb, int wq, const float (&src)[8]) {
        const int f = (wq >> 1) & 3;
        u32x4 pk;
        pk[0] = (unsigned)f2bf(src[0]) | ((unsigned)f2bf(src[1]) << 16);
        pk[1] = (unsigned)f2bf(src[2]) | ((unsigned)f2bf(src[3]) << 16);
        pk[2] = (unsigned)f2bf(src[4]) | ((unsigned)f2bf(src[5]) << 16);
        pk[3] = (unsigned)f2bf(src[6]) | ((unsigned)f2bf(src[7]) << 16);
        lds[(slot * WSPAN + wq) * 4 + (cb ^ f)] = pk;
    };
    auto frag_read = [&](int slot, int wq) -> bf16x8 {
        const int f = (wq >> 1) & 3;
        union { u32x4 u; bf16x8 v; } cv;
        cv.u = lds[(slot * WSPAN + wq) * 4 + (lq ^ f)];
        return cv.v;
    };

    // ---- accumulators: 3-row ring x 4 pixel groups ----
    f32x4 acc[3][4];
    const f32x4 zero = {0.f, 0.f, 0.f, 0.f};
    #pragma unroll
    for (int a = 0; a < 3; ++a)
        #pragma unroll
        for (int pg = 0; pg < 4; ++pg) acc[a][pg] = zero;

    // per-thread output base: o = wid*16 + lq*4 (+j), w = W0 + lr (+pg*16)
    float* obase = out + (((n * 64 + wid * 16 + lq * 4) * 128) * 128) + W0 + lr;

    // ---- prologue: 2-row-deep pipeline fill ----
    // staged row rho <-> global row H0-1+rho ; buf parity = rho & 1
    float bufA[2][8], bufB[2][8];
    issue_loads(H0 - 1, cb0, wq0, bufA[0]);
    if (hasB) issue_loads(H0 - 1, cb1, wq1, bufB[0]);
    issue_loads(H0, cb0, wq0, bufA[1]);
    if (hasB) issue_loads(H0, cb1, wq1, bufB[1]);

    lds_write(0, cb0, wq0, bufA[0]);
    if (hasB) lds_write(0, cb1, wq1, bufB[0]);
    issue_loads(H0 + 1, cb0, wq0, bufA[0]);            // staged row 2
    if (hasB) issue_loads(H0 + 1, cb1, wq1, bufB[0]);

    lds_write(1, cb0, wq0, bufA[1]);
    if (hasB) lds_write(1, cb1, wq1, bufB[1]);
    issue_loads(H0 + 2, cb0, wq0, bufA[1]);            // staged row 3
    if (hasB) issue_loads(H0 + 2, cb1, wq1, bufB[1]);
    rowsync();

    // ---- one fully-static row iteration (RHO is a literal) ----
    // staged row RHO in slot RHO%4 feeds h = H0+RHO-ki; h done at RHO=h-H0+2.
#define ROW(RHO)                                                              \
    {                                                                         \
        _Pragma("unroll")                                                     \
        for (int pg = 0; pg < 4; ++pg) {                                      \
            _Pragma("unroll")                                                 \
            for (int kj = 0; kj < 3; ++kj) {                                  \
                const bf16x8 fb = frag_read((RHO) % 4, pg * 16 + lr + kj);    \
                _Pragma("unroll")                                             \
                for (int ki = 0; ki < 3; ++ki) {                              \
                    if ((RHO) - ki < 0 || (RHO) - ki > HT - 1) continue;      \
                    acc[((RHO) - ki + 1) % 3][pg] =                           \
                        __builtin_amdgcn_mfma_f32_16x16x32_bf16(              \
                            wA[ki * 3 + kj], fb,                              \
                            acc[((RHO) - ki + 1) % 3][pg], 0, 0, 0);          \
                }                                                             \
            }                                                                 \
        }                                                                     \
        if ((RHO) + 2 < NROWS) {                                              \
            lds_write(((RHO) + 2) % 4, cb0, wq0, bufA[(RHO) & 1]);            \
            if (hasB) lds_write(((RHO) + 2) % 4, cb1, wq1, bufB[(RHO) & 1]);  \
        }                                                                     \
        if ((RHO) + 4 < NROWS) {                                              \
            issue_loads(H0 + (RHO) + 3, cb0, wq0, bufA[(RHO) & 1]);           \
            if (hasB) issue_loads(H0 + (RHO) + 3, cb1, wq1, bufB[(RHO) & 1]); \
        }                                                                     \
        if ((RHO) >= 2) {                                                     \
            const int h = H0 + (RHO) - 2;                                     \
            _Pragma("unroll")                                                 \
            for (int pg = 0; pg < 4; ++pg) {                                  \
                _Pragma("unroll")                                             \
                for (int j = 0; j < 4; ++j)                                   \
                    obase[(j * 128 + h) * 128 + pg * 16] =                    \
                        acc[((RHO) - 1) % 3][pg][j];                          \
                acc[((RHO) - 1) % 3][pg] = zero;                              \
            }                                                                 \
        }                                                                     \
        if ((RHO) < NROWS - 1) rowsync();                                     \
    }

    ROW(0) ROW(1) ROW(2) ROW(3) ROW(4) ROW(5) ROW(6) ROW(7) ROW(8) ROW(9)
#undef ROW
}

extern "C" void kernel_launch(void* const* d_in, const int* in_sizes, int n_in,
                              void* d_out, int out_size, void* d_ws, size_t ws_size,
                              hipStream_t stream) {
    const float* x  = (const float*)d_in[0];
    const float* wk = (const float*)d_in[1];
    float* out = (float*)d_out;
    dim3 grid(16, 2, 32);   // hb, wh, n  -> 1024 blocks = 4 per CU
    dim3 block(256);
    conv3x3_mfma<<<grid, block, 0, stream>>>(x, wk, out);
}

// Round 5
// 60.154 us; speedup vs baseline: 1.1958x; 1.1958x over previous
//
#include <hip/hip_runtime.h>

typedef __attribute__((ext_vector_type(8))) short   bf16x8;
typedef __attribute__((ext_vector_type(4))) float   f32x4;
typedef __attribute__((ext_vector_type(4))) unsigned int u32x4;

#define HT 8           // output rows per block (main kernel)

__device__ __forceinline__ unsigned short f2bf(float f) {
    union { float f; unsigned u; } v; v.f = f;
    unsigned u = v.u;
    u += 0x7FFFu + ((u >> 16) & 1u);   // RNE
    return (unsigned short)(u >> 16);
}

// ---------------------------------------------------------------------------
// Pre-pass: x (N=32, C=32, H=128, W=128) f32 NCHW  ->  x_t NHWC bf16
// x_t[n][h][w][c], c contiguous (64B per pixel). One (n,h,wh) per block.
// ---------------------------------------------------------------------------
__global__ __launch_bounds__(256, 4)
void nchw_to_nhwc_bf16(const float* __restrict__ x, unsigned short* __restrict__ xt) {
    const int wh = blockIdx.x, h = blockIdx.y, n = blockIdx.z;
    const int tid = threadIdx.x;
    const int cb = tid >> 6, w = tid & 63;       // c-octet, w within 64
    const int wg = wh * 64 + w;

    __shared__ u32x4 tile[64 * 5];               // [w][cb] padded stride 5

    const float* p = x + (((n * 32 + cb * 8) * 128 + h) * 128 + wg);
    float v[8];
    #pragma unroll
    for (int j = 0; j < 8; ++j) v[j] = p[j * 16384];
    u32x4 pk;
    pk[0] = (unsigned)f2bf(v[0]) | ((unsigned)f2bf(v[1]) << 16);
    pk[1] = (unsigned)f2bf(v[2]) | ((unsigned)f2bf(v[3]) << 16);
    pk[2] = (unsigned)f2bf(v[4]) | ((unsigned)f2bf(v[5]) << 16);
    pk[3] = (unsigned)f2bf(v[6]) | ((unsigned)f2bf(v[7]) << 16);
    tile[w * 5 + cb] = pk;
    __syncthreads();

    // linear contiguous write: thread tid emits 16B for (pixel tid>>2, octet tid&3)
    u32x4* dst = (u32x4*)(xt + (((n * 128 + h) * 128) + wh * 64) * 32);
    dst[tid] = tile[(tid >> 2) * 5 + (tid & 3)];
}

// ---------------------------------------------------------------------------
// Main conv: zero LDS, zero barriers. Each wave owns one 16-och tile of a
// (n, 8h x 64w) output tile; B-fragments loaded directly from x_t (bf16 NHWC).
// ---------------------------------------------------------------------------
__global__ __launch_bounds__(256, 4)
void conv3x3_mfma(const unsigned short* __restrict__ xt,
                  const float* __restrict__ wk,
                  float* __restrict__ out) {
    const int hb = blockIdx.x, wh = blockIdx.y, n = blockIdx.z;
    const int H0 = hb * HT, W0 = wh * 64;
    const int lane = threadIdx.x & 63, wid = threadIdx.x >> 6;
    const int lq = lane >> 4, lr = lane & 15;

    // ---- weights -> registers: wave `wid` owns och tile [wid*16, wid*16+16) ----
    // Raw buffer index: ((c*3+ki)*3+kj)*64 + o   (reshape quirk).
    bf16x8 wA[9];
    #pragma unroll
    for (int p = 0; p < 9; ++p) {
        const int ki = p / 3, kj = p % 3;
        union { bf16x8 v; unsigned short s[8]; } u;
        #pragma unroll
        for (int j = 0; j < 8; ++j) {
            const int c = lq * 8 + j;
            u.s[j] = f2bf(wk[((c * 3 + ki) * 3 + kj) * 64 + wid * 16 + lr]);
        }
        wA[p] = u.v;
    }

    // B-fragment: 8 contiguous bf16 channels at (rg, wg), zero outside w range
    auto bload = [&](int rg, int wg) -> bf16x8 {
        union { u32x4 u; bf16x8 v; } cv;
        cv.u = (u32x4){0u, 0u, 0u, 0u};
        if ((unsigned)wg < 128u)
            cv.u = *(const u32x4*)(xt + (((n * 128 + rg) * 128 + wg) * 32) + lq * 8);
        return cv.v;
    };

    // ---- accumulators: 3-row ring x 4 pixel groups ----
    f32x4 acc[3][4];
    const f32x4 zero = {0.f, 0.f, 0.f, 0.f};
    #pragma unroll
    for (int a = 0; a < 3; ++a)
        #pragma unroll
        for (int pg = 0; pg < 4; ++pg) acc[a][pg] = zero;

    // per-thread output base: o = wid*16 + lq*4 (+j), w = W0 + lr (+pg*16)
    float* obase = out + (((n * 64 + wid * 16 + lq * 4) * 128) * 128) + W0 + lr;

    // ---- fully-static row iterations; input row rg = H0+RHO-1 feeds output
    //      rows h = H0+RHO-ki; output row h completes at RHO = h-H0+2. ----
#define ROW(RHO)                                                              \
    {                                                                         \
        const int rg = H0 + (RHO) - 1;                                        \
        if ((unsigned)rg < 128u) {                                            \
            _Pragma("unroll")                                                 \
            for (int pg = 0; pg < 4; ++pg) {                                  \
                const int wb = W0 + pg * 16 + lr - 1;                         \
                const bf16x8 fb0 = bload(rg, wb);                             \
                const bf16x8 fb1 = bload(rg, wb + 1);                         \
                const bf16x8 fb2 = bload(rg, wb + 2);                         \
                _Pragma("unroll")                                             \
                for (int ki = 0; ki < 3; ++ki) {                              \
                    if ((RHO) - ki < 0 || (RHO) - ki > HT - 1) continue;      \
                    const int a = ((RHO) - ki + 1) % 3;                       \
                    acc[a][pg] = __builtin_amdgcn_mfma_f32_16x16x32_bf16(     \
                        wA[ki * 3 + 0], fb0, acc[a][pg], 0, 0, 0);            \
                    acc[a][pg] = __builtin_amdgcn_mfma_f32_16x16x32_bf16(     \
                        wA[ki * 3 + 1], fb1, acc[a][pg], 0, 0, 0);            \
                    acc[a][pg] = __builtin_amdgcn_mfma_f32_16x16x32_bf16(     \
                        wA[ki * 3 + 2], fb2, acc[a][pg], 0, 0, 0);            \
                }                                                             \
            }                                                                 \
        }                                                                     \
        if ((RHO) >= 2) {                                                     \
            const int h = H0 + (RHO) - 2;                                     \
            const int a = ((RHO) - 1) % 3;                                    \
            _Pragma("unroll")                                                 \
            for (int pg = 0; pg < 4; ++pg) {                                  \
                _Pragma("unroll")                                             \
                for (int j = 0; j < 4; ++j)                                   \
                    obase[(j * 128 + h) * 128 + pg * 16] = acc[a][pg][j];     \
                acc[a][pg] = zero;                                            \
            }                                                                 \
        }                                                                     \
    }

    ROW(0) ROW(1) ROW(2) ROW(3) ROW(4) ROW(5) ROW(6) ROW(7) ROW(8) ROW(9)
#undef ROW
}

extern "C" void kernel_launch(void* const* d_in, const int* in_sizes, int n_in,
                              void* d_out, int out_size, void* d_ws, size_t ws_size,
                              hipStream_t stream) {
    const float* x  = (const float*)d_in[0];
    const float* wk = (const float*)d_in[1];
    float* out = (float*)d_out;
    unsigned short* xt = (unsigned short*)d_ws;   // 32*128*128*32 bf16 = 32 MiB

    {   // pre-pass: NCHW f32 -> NHWC bf16
        dim3 grid(2, 128, 32);   // wh, h, n
        nchw_to_nhwc_bf16<<<grid, dim3(256), 0, stream>>>(x, xt);
    }
    {   // main conv
        dim3 grid(16, 2, 32);    // hb, wh, n  -> 1024 blocks
        conv3x3_mfma<<<grid, dim3(256), 0, stream>>>(xt, wk, out);
    }
}

// Round 6
// 59.938 us; speedup vs baseline: 1.2001x; 1.0036x over previous
//
#include <hip/hip_runtime.h>

typedef __attribute__((ext_vector_type(8))) short   bf16x8;
typedef __attribute__((ext_vector_type(4))) float   f32x4;
typedef __attribute__((ext_vector_type(4))) unsigned int u32x4;

#define HT 8           // output rows per block (main kernel)
#define XT_W 130       // padded pixel stride: col 0 and col 129 are zero

__device__ __forceinline__ unsigned short f2bf(float f) {
    union { float f; unsigned u; } v; v.f = f;
    unsigned u = v.u;
    u += 0x7FFFu + ((u >> 16) & 1u);   // RNE
    return (unsigned short)(u >> 16);
}

// ---------------------------------------------------------------------------
// Pre-pass: x (N=32, C=32, H=128, W=128) f32 NCHW -> x_t (N,H,130,32) bf16,
// c contiguous (64B per pixel), pixel index p = w+1, cols 0 & 129 zeroed.
// ---------------------------------------------------------------------------
__global__ __launch_bounds__(256, 4)
void nchw_to_nhwc_bf16(const float* __restrict__ x, unsigned short* __restrict__ xt) {
    const int wh = blockIdx.x, h = blockIdx.y, n = blockIdx.z;
    const int tid = threadIdx.x;
    const int cb = tid >> 6, w = tid & 63;       // c-octet, w within 64
    const int wg = wh * 64 + w;

    __shared__ u32x4 tile[64 * 5];               // [w][cb] padded stride 5

    const float* p = x + (((n * 32 + cb * 8) * 128 + h) * 128 + wg);
    float v[8];
    #pragma unroll
    for (int j = 0; j < 8; ++j) v[j] = p[j * 16384];
    u32x4 pk;
    pk[0] = (unsigned)f2bf(v[0]) | ((unsigned)f2bf(v[1]) << 16);
    pk[1] = (unsigned)f2bf(v[2]) | ((unsigned)f2bf(v[3]) << 16);
    pk[2] = (unsigned)f2bf(v[4]) | ((unsigned)f2bf(v[5]) << 16);
    pk[3] = (unsigned)f2bf(v[6]) | ((unsigned)f2bf(v[7]) << 16);
    tile[w * 5 + cb] = pk;
    __syncthreads();

    // contiguous write: thread tid emits 16B for (pixel tid>>2, octet tid&3)
    u32x4* dst = (u32x4*)xt;
    const int base = ((n * 128 + h) * XT_W + 1 + wh * 64) * 4;
    dst[base + tid] = tile[(tid >> 2) * 5 + (tid & 3)];

    // zero border columns (p=0 handled by wh==0 blocks, p=129 by wh==1)
    if (tid < 4) {
        const u32x4 z = {0u, 0u, 0u, 0u};
        const int col = (wh == 0) ? 0 : 129;
        dst[((n * 128 + h) * XT_W + col) * 4 + tid] = z;
    }
}

// ---------------------------------------------------------------------------
// Main conv: zero LDS, zero barriers, zero per-row OOB logic. Each wave owns
// one 16-och tile of a (n, 8h x 64w) tile; B-frags load straight from x_t
// via SGPR row base + constant per-lane voffset.
// ---------------------------------------------------------------------------
__global__ __launch_bounds__(256, 4)
void conv3x3_mfma(const unsigned short* __restrict__ xt,
                  const float* __restrict__ wk,
                  float* __restrict__ out) {
    const int hb = blockIdx.x, wh = blockIdx.y, n = blockIdx.z;
    const int H0 = hb * HT, W0 = wh * 64;
    const int lane = threadIdx.x & 63, wid = threadIdx.x >> 6;
    const int lq = lane >> 4, lr = lane & 15;

    // ---- weights -> registers: wave `wid` owns och tile [wid*16, wid*16+16) ----
    // Raw buffer index: ((c*3+ki)*3+kj)*64 + o   (reshape quirk).
    bf16x8 wA[9];
    #pragma unroll
    for (int p = 0; p < 9; ++p) {
        const int ki = p / 3, kj = p % 3;
        union { bf16x8 v; unsigned short s[8]; } u;
        #pragma unroll
        for (int j = 0; j < 8; ++j) {
            const int c = lq * 8 + j;
            u.s[j] = f2bf(wk[((c * 3 + ki) * 3 + kj) * 64 + wid * 16 + lr]);
        }
        wA[p] = u.v;
    }

    // ---- accumulators: 3-row ring x 4 pixel groups ----
    f32x4 acc[3][4];
    const f32x4 zero = {0.f, 0.f, 0.f, 0.f};
    #pragma unroll
    for (int a = 0; a < 3; ++a)
        #pragma unroll
        for (int pg = 0; pg < 4; ++pg) acc[a][pg] = zero;

    // per-thread output base: o = wid*16 + lq*4 (+j), w = W0 + lr (+pg*16)
    float* obase = out + (((n * 64 + wid * 16 + lq * 4) * 128) * 128) + W0 + lr;

    // per-lane constant element offsets within a row: pixel p = W0+pg*16+lr+kj
    // (wg = p-1 in [-1,128] is always in-bounds thanks to the zero pad cols)
    // elem = p*32 + lq*8 ; row base is wave-uniform.
#define VOFF(PG, KJ) ((W0 + (PG) * 16 + lr + (KJ)) * 32 + lq * 8)

#define ROW(RHO)                                                              \
    {                                                                         \
        const int rg = H0 + (RHO) - 1;                                        \
        if ((unsigned)rg < 128u) {                                            \
            const unsigned short* rowp = xt + (size_t)(n * 128 + rg) * (XT_W * 32); \
            _Pragma("unroll")                                                 \
            for (int pg = 0; pg < 4; ++pg) {                                  \
                const bf16x8 fb0 = *(const bf16x8*)(rowp + VOFF(pg, 0));      \
                const bf16x8 fb1 = *(const bf16x8*)(rowp + VOFF(pg, 1));      \
                const bf16x8 fb2 = *(const bf16x8*)(rowp + VOFF(pg, 2));      \
                _Pragma("unroll")                                             \
                for (int ki = 0; ki < 3; ++ki) {                              \
                    if ((RHO) - ki < 0 || (RHO) - ki > HT - 1) continue;      \
                    const int a = ((RHO) - ki + 1) % 3;                       \
                    acc[a][pg] = __builtin_amdgcn_mfma_f32_16x16x32_bf16(     \
                        wA[ki * 3 + 0], fb0, acc[a][pg], 0, 0, 0);            \
                    acc[a][pg] = __builtin_amdgcn_mfma_f32_16x16x32_bf16(     \
                        wA[ki * 3 + 1], fb1, acc[a][pg], 0, 0, 0);            \
                    acc[a][pg] = __builtin_amdgcn_mfma_f32_16x16x32_bf16(     \
                        wA[ki * 3 + 2], fb2, acc[a][pg], 0, 0, 0);            \
                }                                                             \
            }                                                                 \
        }                                                                     \
        if ((RHO) >= 2) {                                                     \
            const int h = H0 + (RHO) - 2;                                     \
            const int a = ((RHO) - 1) % 3;                                    \
            _Pragma("unroll")                                                 \
            for (int pg = 0; pg < 4; ++pg) {                                  \
                _Pragma("unroll")                                             \
                for (int j = 0; j < 4; ++j)                                   \
                    obase[(j * 128 + h) * 128 + pg * 16] = acc[a][pg][j];     \
                acc[a][pg] = zero;                                            \
            }                                                                 \
        }                                                                     \
    }

    ROW(0) ROW(1) ROW(2) ROW(3) ROW(4) ROW(5) ROW(6) ROW(7) ROW(8) ROW(9)
#undef ROW
#undef VOFF
}

extern "C" void kernel_launch(void* const* d_in, const int* in_sizes, int n_in,
                              void* d_out, int out_size, void* d_ws, size_t ws_size,
                              hipStream_t stream) {
    const float* x  = (const float*)d_in[0];
    const float* wk = (const float*)d_in[1];
    float* out = (float*)d_out;
    unsigned short* xt = (unsigned short*)d_ws;   // 32*128*130*32 bf16 = 34 MiB

    {   // pre-pass: NCHW f32 -> padded NHWC bf16 (+ zeroed border cols)
        dim3 grid(2, 128, 32);   // wh, h, n
        nchw_to_nhwc_bf16<<<grid, dim3(256), 0, stream>>>(x, xt);
    }
    {   // main conv
        dim3 grid(16, 2, 32);    // hb, wh, n  -> 1024 blocks = 4 per CU
        conv3x3_mfma<<<grid, dim3(256), 0, stream>>>(xt, wk, out);
    }
}